// Round 2
// baseline (277.353 us; speedup 1.0000x reference)
//
#include <hip/hip_runtime.h>
#include <math.h>

#define TT 100
#define NN 100
#define DD 1024
#define HH 8192
#define ILR 0.01f

__device__ __forceinline__ float wave_sum64(float v) {
#pragma unroll
  for (int off = 32; off; off >>= 1) v += __shfl_xor(v, off, 64);
  return v;
}

// ---------------- K1 (split-K): preact[r][j] += sum_{k in slice} Xall[r][k]*W[k][j]
// grid = 2048 blocks, decoded so the 4 row-sibling blocks (sharing a W col-tile)
// land on the same XCD (flat%8 round-robin assumption; harmless if wrong).
__global__ __launch_bounds__(256) void k1_splitk(const float* __restrict__ xt,
                                                 const float* __restrict__ xr,
                                                 const float* __restrict__ W,
                                                 float* __restrict__ preact) {
  __shared__ float As[16 * 68];  // [k][row], stride 68
  __shared__ float Bs[16 * 64];  // [k][col]
  const int flat = blockIdx.x;
  const int pair_lo = flat & 7;
  const int x = (flat >> 3) & 3;        // row tile 0..3
  const int pair_hi = flat >> 5;
  const int pair = pair_lo + 8 * pair_hi;  // 0..511 = ytile + 128*z
  const int ytile = pair & 127;
  const int z = pair >> 7;              // k-slice 0..3
  const int tid = threadIdx.x;
  const int row0 = x * 64;
  const int col0 = ytile * 64;
  const int kbase = z * 256;
  const int tx = tid & 15, ty = tid >> 4;
  const int lr_ = tid >> 2;  // 0..63 A-load row
  const int lkq = tid & 3;   // 0..3
  const int lbk = tid >> 4;  // 0..15 B-load k
  const int lbj = (tid & 15) * 4;

  float acc[4][4];
#pragma unroll
  for (int i = 0; i < 4; i++)
#pragma unroll
    for (int j = 0; j < 4; j++) acc[i][j] = 0.f;

  for (int k0 = kbase; k0 < kbase + 256; k0 += 16) {
    float4 av;
    const int grow = row0 + lr_;
    if (grow < 200) {
      const float* src = (grow < TT) ? (xt + grow * DD) : (xr + (grow - TT) * DD);
      av = *(const float4*)(src + k0 + lkq * 4);
    } else {
      av = make_float4(0.f, 0.f, 0.f, 0.f);
    }
    const float4 bv = *(const float4*)(W + (k0 + lbk) * HH + col0 + lbj);
    __syncthreads();
    As[(lkq * 4 + 0) * 68 + lr_] = av.x;
    As[(lkq * 4 + 1) * 68 + lr_] = av.y;
    As[(lkq * 4 + 2) * 68 + lr_] = av.z;
    As[(lkq * 4 + 3) * 68 + lr_] = av.w;
    *(float4*)&Bs[lbk * 64 + lbj] = bv;
    __syncthreads();
#pragma unroll
    for (int k = 0; k < 16; k++) {
      const float4 a4 = *(const float4*)&As[k * 68 + ty * 4];
      const float4 b4 = *(const float4*)&Bs[k * 64 + tx * 4];
      const float a_[4] = {a4.x, a4.y, a4.z, a4.w};
      const float b_[4] = {b4.x, b4.y, b4.z, b4.w};
#pragma unroll
      for (int i = 0; i < 4; i++)
#pragma unroll
        for (int j = 0; j < 4; j++) acc[i][j] = fmaf(a_[i], b_[j], acc[i][j]);
    }
  }
#pragma unroll
  for (int i = 0; i < 4; i++) {
    const int r = row0 + ty * 4 + i;
    if (r < 200) {
      float* dst = preact + r * HH + col0 + tx * 4;
      atomicAdd(dst + 0, acc[i][0]);
      atomicAdd(dst + 1, acc[i][1]);
      atomicAdd(dst + 2, acc[i][2]);
      atomicAdd(dst + 3, acc[i][3]);
    }
  }
}

// ---------------- K1b: Hall = tanh(preact + bias)
__global__ __launch_bounds__(256) void k1b_tanh(const float* __restrict__ preact,
                                                const float* __restrict__ bias,
                                                float* __restrict__ Hall) {
  const int idx4 = (blockIdx.x * 256 + threadIdx.x) * 4;  // 200*8192 total
  const int c = idx4 & (HH - 1);
  const float4 p = *(const float4*)(preact + idx4);
  const float4 b = *(const float4*)(bias + c);
  float4 h;
  h.x = tanhf(p.x + b.x);
  h.y = tanhf(p.y + b.y);
  h.z = tanhf(p.z + b.z);
  h.w = tanhf(p.w + b.w);
  *(float4*)(Hall + idx4) = h;
}

// ---------------- K2: Gram G[s][t] = Ht[s]·Ht[t] (2x2 tiles per wave) + y0[t] = Ht[t]·w0
__global__ __launch_bounds__(256) void k2_gram(const float* __restrict__ Ht,
                                               const float* __restrict__ w0,
                                               float* __restrict__ G,
                                               float* __restrict__ y0) {
  const int wid = blockIdx.x * 4 + (threadIdx.x >> 6);
  const int lane = threadIdx.x & 63;
  if (wid < 1275) {
    int a = 0, rem = wid;
    while (rem >= 50 - a) { rem -= 50 - a; a++; }
    const int bt = a + rem;
    const int s0 = a * 2, t0 = bt * 2;
    const float* r0 = Ht + s0 * HH;
    const float* r1 = Ht + (s0 + 1) * HH;
    const float* c0 = Ht + t0 * HH;
    const float* c1 = Ht + (t0 + 1) * HH;
    float a00 = 0.f, a01 = 0.f, a10 = 0.f, a11 = 0.f;
#pragma unroll 4
    for (int i = 0; i < 32; i++) {
      const int k = (lane + i * 64) * 4;
      const float4 x0 = *(const float4*)(r0 + k);
      const float4 x1 = *(const float4*)(r1 + k);
      const float4 u0 = *(const float4*)(c0 + k);
      const float4 u1 = *(const float4*)(c1 + k);
      a00 += x0.x * u0.x + x0.y * u0.y + x0.z * u0.z + x0.w * u0.w;
      a01 += x0.x * u1.x + x0.y * u1.y + x0.z * u1.z + x0.w * u1.w;
      a10 += x1.x * u0.x + x1.y * u0.y + x1.z * u0.z + x1.w * u0.w;
      a11 += x1.x * u1.x + x1.y * u1.y + x1.z * u1.z + x1.w * u1.w;
    }
    a00 = wave_sum64(a00);
    a01 = wave_sum64(a01);
    a10 = wave_sum64(a10);
    a11 = wave_sum64(a11);
    if (lane == 0) {
      G[s0 * 100 + t0] = a00;             G[t0 * 100 + s0] = a00;
      G[s0 * 100 + t0 + 1] = a01;         G[(t0 + 1) * 100 + s0] = a01;
      G[(s0 + 1) * 100 + t0] = a10;       G[t0 * 100 + s0 + 1] = a10;
      G[(s0 + 1) * 100 + t0 + 1] = a11;   G[(t0 + 1) * 100 + s0 + 1] = a11;
    }
  } else if (wid < 1300) {
    const int t0 = (wid - 1275) * 4;
    const float* r0 = Ht + t0 * HH;
    const float* r1 = r0 + HH;
    const float* r2 = r1 + HH;
    const float* r3 = r2 + HH;
    float a0 = 0.f, a1 = 0.f, a2 = 0.f, a3 = 0.f;
#pragma unroll 4
    for (int i = 0; i < 32; i++) {
      const int k = (lane + i * 64) * 4;
      const float4 wv = *(const float4*)(w0 + k);
      const float4 x0 = *(const float4*)(r0 + k);
      const float4 x1 = *(const float4*)(r1 + k);
      const float4 x2 = *(const float4*)(r2 + k);
      const float4 x3 = *(const float4*)(r3 + k);
      a0 += x0.x * wv.x + x0.y * wv.y + x0.z * wv.z + x0.w * wv.w;
      a1 += x1.x * wv.x + x1.y * wv.y + x1.z * wv.z + x1.w * wv.w;
      a2 += x2.x * wv.x + x2.y * wv.y + x2.z * wv.z + x2.w * wv.w;
      a3 += x3.x * wv.x + x3.y * wv.y + x3.z * wv.z + x3.w * wv.w;
    }
    a0 = wave_sum64(a0);
    a1 = wave_sum64(a1);
    a2 = wave_sum64(a2);
    a3 = wave_sum64(a3);
    if (lane == 0) {
      y0[t0] = a0;
      y0[t0 + 1] = a1;
      y0[t0 + 2] = a2;
      y0[t0 + 3] = a3;
    }
  }
}

// ---------------- K3: sequential scalar solve for err_t (1 wave)
__global__ __launch_bounds__(64) void k3_solve(const float* __restrict__ G,
                                               const float* __restrict__ y0,
                                               const float* __restrict__ ytraj,
                                               float* __restrict__ errT) {
  __shared__ float Gs[100 * 101];  // stride 101 -> conflict-free column reads
  __shared__ float y0s[100];
  __shared__ float tgt[100];
  const int l = threadIdx.x;
  for (int idx = l; idx < 10000; idx += 64) {
    Gs[(idx / 100) * 101 + (idx % 100)] = G[idx];
  }
  if (l < 50) {
    y0s[l] = y0[l];       y0s[l + 50] = y0[l + 50];
    tgt[l] = ytraj[l];    tgt[l + 50] = ytraj[l + 50];
  }
  __syncthreads();
  float e_lo = 0.f, e_hi = 0.f;  // lane l holds err_l and err_{64+l}
  for (int t = 0; t < TT; t++) {
    float contrib = 0.f;
    if (l < t) contrib += e_lo * Gs[l * 101 + t];
    if (l + 64 < t) contrib += e_hi * Gs[(l + 64) * 101 + t];
    contrib = wave_sum64(contrib);
    const float err = tgt[t] - (y0s[t] + ILR * contrib);  // uniform across wave
    if (t < 64) {
      if (l == t) e_lo = err;
    } else {
      if (l == t - 64) e_hi = err;
    }
    if (l == 0) errT[t] = err;
  }
}

// ---------------- K4: per-column forward scan (c_t, w_f) + backward suffix-product
__global__ __launch_bounds__(256) void k4_colscan(const float* __restrict__ Ht,
                                                  const float* __restrict__ errT,
                                                  const float* __restrict__ w0,
                                                  float* __restrict__ Ct,
                                                  float* __restrict__ wf) {
  __shared__ float es[100];
  const int tid = threadIdx.x;
  if (tid < 100) es[tid] = errT[tid];
  __syncthreads();
  const int j = blockIdx.x * 256 + tid;
  float w = w0[j];
#pragma unroll 4
  for (int t = 0; t < TT; t++) {
    const float h = Ht[t * HH + j];
    const float e = es[t];
    const float d = 1.f - h * h;
    w += ILR * e * h;                      // w_new (online update happens first)
    Ct[t * HH + j] = ILR * d * (e - h * w);  // c_t
  }
  wf[j] = w;
  float prod = 1.f;  // suffix product of a_s = 1 - lr*h^2 over s>t
#pragma unroll 4
  for (int t = TT - 1; t >= 0; t--) {
    Ct[t * HH + j] *= prod;
    const float h = Ht[t * HH + j];
    prod *= (1.f - ILR * h * h);
  }
}

// ---------------- K5: e_i = Hrand[i]·w_f - y_rand[i]  (one block per i)
__global__ __launch_bounds__(256) void k5_pred(const float* __restrict__ Hr,
                                               const float* __restrict__ wf,
                                               const float* __restrict__ yr,
                                               float* __restrict__ e_r) {
  const int i = blockIdx.x;
  const int tid = threadIdx.x;
  const float* row = Hr + i * HH;
  float p = 0.f;
#pragma unroll
  for (int c = tid * 4; c < HH; c += 1024) {
    const float4 h4 = *(const float4*)(row + c);
    const float4 w4 = *(const float4*)(wf + c);
    p += h4.x * w4.x + h4.y * w4.y + h4.z * w4.z + h4.w * w4.w;
  }
  p = wave_sum64(p);
  __shared__ float ps[4];
  if ((tid & 63) == 0) ps[tid >> 6] = p;
  __syncthreads();
  if (tid == 0) {
    const float y = ps[0] + ps[1] + ps[2] + ps[3];
    e_r[i] = y - yr[i];
  }
}

// ---------------- K6: v_j, M rows (v*Ct in place; U), gb = colsum(M), loss
__global__ __launch_bounds__(256) void k6_mbuild(const float* __restrict__ Hr,
                                                 const float* __restrict__ e_r,
                                                 const float* __restrict__ wf,
                                                 float* __restrict__ Ct,
                                                 float* __restrict__ U,
                                                 float* __restrict__ gb_out,
                                                 float* __restrict__ loss_out) {
  __shared__ float es[100];
  const int tid = threadIdx.x;
  if (tid < 100) es[tid] = e_r[tid];
  __syncthreads();
  if (blockIdx.x == 0 && tid < 64) {  // wave 0 of block 0: loss
    float s = es[tid] * es[tid];
    if (tid < 36) {
      const float q = es[tid + 64];
      s += q * q;
    }
    s = wave_sum64(s);
    if (tid == 0) loss_out[0] = s / (float)NN;
  }
  const int j = blockIdx.x * 256 + tid;
  const float wfj = wf[j];
  float v = 0.f;
#pragma unroll 4
  for (int i = 0; i < NN; i++) v += es[i] * Hr[i * HH + j];
  float gb = 0.f;
#pragma unroll 4
  for (int t = 0; t < TT; t++) {
    const float m = v * Ct[t * HH + j];
    Ct[t * HH + j] = m;
    gb += m;
  }
#pragma unroll 4
  for (int i = 0; i < NN; i++) {
    const float h = Hr[i * HH + j];
    const float m = es[i] * wfj * (1.f - h * h);
    U[i * HH + j] = m;
    gb += m;
  }
  gb_out[j] = gb;
}

// ---------------- K7: gW[m][j] = sum_k Xall[k][m] * Mmat[k][j]   (K=200)
__global__ __launch_bounds__(256) void k7_gw(const float* __restrict__ xt,
                                             const float* __restrict__ xr,
                                             const float* __restrict__ Mmat,
                                             float* __restrict__ gW) {
  __shared__ float As[16 * 64];  // [k][m]
  __shared__ float Bs[16 * 64];  // [k][j]
  const int tid = threadIdx.x;
  const int m0 = blockIdx.x * 64;
  const int col0 = blockIdx.y * 64;
  const int tx = tid & 15, ty = tid >> 4;
  const int lk = tid >> 4;         // 0..15
  const int lm4 = (tid & 15) * 4;  // 0..60
  float acc[4][4];
#pragma unroll
  for (int i = 0; i < 4; i++)
#pragma unroll
    for (int j = 0; j < 4; j++) acc[i][j] = 0.f;

  for (int k0 = 0; k0 < 208; k0 += 16) {
    const int gk = k0 + lk;
    float4 av, bv;
    if (gk < 200) {
      const float* asrc = (gk < TT) ? (xt + gk * DD) : (xr + (gk - TT) * DD);
      av = *(const float4*)(asrc + m0 + lm4);
      bv = *(const float4*)(Mmat + gk * HH + col0 + lm4);
    } else {
      av = make_float4(0.f, 0.f, 0.f, 0.f);
      bv = av;
    }
    __syncthreads();
    *(float4*)&As[lk * 64 + lm4] = av;
    *(float4*)&Bs[lk * 64 + lm4] = bv;
    __syncthreads();
#pragma unroll
    for (int k = 0; k < 16; k++) {
      const float4 a4 = *(const float4*)&As[k * 64 + ty * 4];
      const float4 b4 = *(const float4*)&Bs[k * 64 + tx * 4];
      const float a_[4] = {a4.x, a4.y, a4.z, a4.w};
      const float b_[4] = {b4.x, b4.y, b4.z, b4.w};
#pragma unroll
      for (int i = 0; i < 4; i++)
#pragma unroll
        for (int j = 0; j < 4; j++) acc[i][j] = fmaf(a_[i], b_[j], acc[i][j]);
    }
  }
  // gW base is d_out+1 (4B-aligned only) -> scalar stores
#pragma unroll
  for (int i = 0; i < 4; i++) {
    float* dst = gW + (m0 + ty * 4 + i) * HH + col0 + tx * 4;
    dst[0] = acc[i][0];
    dst[1] = acc[i][1];
    dst[2] = acc[i][2];
    dst[3] = acc[i][3];
  }
}

extern "C" void kernel_launch(void* const* d_in, const int* in_sizes, int n_in,
                              void* d_out, int out_size, void* d_ws, size_t ws_size,
                              hipStream_t stream) {
  (void)in_sizes; (void)n_in; (void)out_size; (void)ws_size;
  const float* xt = (const float*)d_in[0];   // [100,1024]
  const float* yt = (const float*)d_in[1];   // [100]
  const float* xr = (const float*)d_in[2];   // [100,1024]
  const float* yr = (const float*)d_in[3];   // [100]
  const float* W = (const float*)d_in[4];    // [1024,8192]
  const float* bias = (const float*)d_in[5]; // [8192]
  const float* w0 = (const float*)d_in[6];   // [8192]
  float* out = (float*)d_out;  // [0]=loss, [1..1+D*H)=gW, then gb[H]
  float* ws = (float*)d_ws;

  float* Hall = ws;              // 200*8192 (rows 0..99 Htraj, 100..199 Hrand)
  float* Ht = Hall;
  float* Hr = Hall + TT * HH;
  float* Ct = Hall + 200 * HH;   // 100*8192 -> becomes M rows 0..99
  float* U = Ct + TT * HH;       // 100*8192 -> M rows 100..199 (contiguous!)
  float* preact = Ct;            // alias: 200*8192 spans Ct+U; dead after k1b
  float* G = U + NN * HH;        // 100*100
  float* y0v = G + TT * TT;      // 100
  float* errT = y0v + TT;        // 100
  float* e_r = errT + TT;        // 100
  float* wf = e_r + NN;          // 8192

  hipMemsetAsync(preact, 0, (size_t)200 * HH * sizeof(float), stream);
  k1_splitk<<<2048, 256, 0, stream>>>(xt, xr, W, preact);
  k1b_tanh<<<(200 * HH / 4) / 256, 256, 0, stream>>>(preact, bias, Hall);
  k2_gram<<<325, 256, 0, stream>>>(Ht, w0, G, y0v);
  k3_solve<<<1, 64, 0, stream>>>(G, y0v, yt, errT);
  k4_colscan<<<HH / 256, 256, 0, stream>>>(Ht, errT, w0, Ct, wf);
  k5_pred<<<NN, 256, 0, stream>>>(Hr, wf, yr, e_r);
  k6_mbuild<<<HH / 256, 256, 0, stream>>>(Hr, e_r, wf, Ct, U, out + 1 + DD * HH, out);
  k7_gw<<<dim3(DD / 64, HH / 64), 256, 0, stream>>>(xt, xr, Ct, out + 1);
}

// Round 3
// 225.959 us; speedup vs baseline: 1.2274x; 1.2274x over previous
//
#include <hip/hip_runtime.h>
#include <math.h>

#define TT 100
#define NN 100
#define DD 1024
#define HH 8192
#define ILR 0.01f

__device__ __forceinline__ float wave_sum64(float v) {
#pragma unroll
  for (int off = 32; off; off >>= 1) v += __shfl_xor(v, off, 64);
  return v;
}

// ---------------- K1: Hall = tanh(Xall @ W + b), intra-block split-K.
// 512 blocks x 1024 threads. Block = (row-tile x, col-tile y); 4 k-groups of
// 256 threads each accumulate K-slice of 256 into registers, combine in LDS
// (deterministic sequential adds), then bias+tanh+store. 32 waves/CU.
__global__ __launch_bounds__(1024) void k1_hidden2(const float* __restrict__ xt,
                                                   const float* __restrict__ xr,
                                                   const float* __restrict__ W,
                                                   const float* __restrict__ bias,
                                                   float* __restrict__ Hall) {
  __shared__ float As[4][16 * 68];  // per-group [k][row], stride 68
  __shared__ float Bs[4][16 * 64];  // per-group [k][col]
  __shared__ float Cs[64 * 64];     // combine buffer
  const int tid = threadIdx.x;
  const int g = tid >> 8;    // k-group 0..3
  const int t = tid & 255;   // thread within group
  const int row0 = (blockIdx.x & 3) * 64;
  const int col0 = (blockIdx.x >> 2) * 64;
  const int kbase = g * 256;
  const int tx = t & 15, ty = t >> 4;
  const int lr_ = t >> 2;  // 0..63 A-load row
  const int lkq = t & 3;   // 0..3
  const int lbk = t >> 4;  // 0..15 B-load k
  const int lbj = (t & 15) * 4;

  float acc[4][4];
#pragma unroll
  for (int i = 0; i < 4; i++)
#pragma unroll
    for (int j = 0; j < 4; j++) acc[i][j] = 0.f;

  for (int k0 = kbase; k0 < kbase + 256; k0 += 16) {
    float4 av;
    const int grow = row0 + lr_;
    if (grow < 200) {
      const float* src = (grow < TT) ? (xt + grow * DD) : (xr + (grow - TT) * DD);
      av = *(const float4*)(src + k0 + lkq * 4);
    } else {
      av = make_float4(0.f, 0.f, 0.f, 0.f);
    }
    const float4 bv = *(const float4*)(W + (k0 + lbk) * HH + col0 + lbj);
    __syncthreads();
    As[g][(lkq * 4 + 0) * 68 + lr_] = av.x;
    As[g][(lkq * 4 + 1) * 68 + lr_] = av.y;
    As[g][(lkq * 4 + 2) * 68 + lr_] = av.z;
    As[g][(lkq * 4 + 3) * 68 + lr_] = av.w;
    *(float4*)&Bs[g][lbk * 64 + lbj] = bv;
    __syncthreads();
#pragma unroll
    for (int k = 0; k < 16; k++) {
      const float4 a4 = *(const float4*)&As[g][k * 68 + ty * 4];
      const float4 b4 = *(const float4*)&Bs[g][k * 64 + tx * 4];
      const float a_[4] = {a4.x, a4.y, a4.z, a4.w};
      const float b_[4] = {b4.x, b4.y, b4.z, b4.w};
#pragma unroll
      for (int i = 0; i < 4; i++)
#pragma unroll
        for (int j = 0; j < 4; j++) acc[i][j] = fmaf(a_[i], b_[j], acc[i][j]);
    }
  }
  // deterministic combine: group 0 writes, groups 1..3 add in order
  __syncthreads();
  if (g == 0) {
#pragma unroll
    for (int i = 0; i < 4; i++)
      *(float4*)&Cs[(ty * 4 + i) * 64 + tx * 4] =
          make_float4(acc[i][0], acc[i][1], acc[i][2], acc[i][3]);
  }
  __syncthreads();
#pragma unroll
  for (int gg = 1; gg < 4; gg++) {
    if (g == gg) {
#pragma unroll
      for (int i = 0; i < 4; i++) {
        float* p = &Cs[(ty * 4 + i) * 64 + tx * 4];
        p[0] += acc[i][0];
        p[1] += acc[i][1];
        p[2] += acc[i][2];
        p[3] += acc[i][3];
      }
    }
    __syncthreads();
  }
  // bias + tanh + store: 1024 threads x 1 float4 = 64x64 tile
  const int rr = tid >> 4;
  const int cc = (tid & 15) * 4;
  if (row0 + rr < 200) {
    const float4 c = *(const float4*)&Cs[rr * 64 + cc];
    const float4 b = *(const float4*)(bias + col0 + cc);
    float4 h;
    h.x = tanhf(c.x + b.x);
    h.y = tanhf(c.y + b.y);
    h.z = tanhf(c.z + b.z);
    h.w = tanhf(c.w + b.w);
    *(float4*)(Hall + (row0 + rr) * HH + col0 + cc) = h;
  }
}

// ---------------- K2: Gram G[s][t] = Ht[s]·Ht[t] (2x2 tiles per wave) + y0[t] = Ht[t]·w0
__global__ __launch_bounds__(256) void k2_gram(const float* __restrict__ Ht,
                                               const float* __restrict__ w0,
                                               float* __restrict__ G,
                                               float* __restrict__ y0) {
  const int wid = blockIdx.x * 4 + (threadIdx.x >> 6);
  const int lane = threadIdx.x & 63;
  if (wid < 1275) {
    int a = 0, rem = wid;
    while (rem >= 50 - a) { rem -= 50 - a; a++; }
    const int bt = a + rem;
    const int s0 = a * 2, t0 = bt * 2;
    const float* r0 = Ht + s0 * HH;
    const float* r1 = Ht + (s0 + 1) * HH;
    const float* c0 = Ht + t0 * HH;
    const float* c1 = Ht + (t0 + 1) * HH;
    float a00 = 0.f, a01 = 0.f, a10 = 0.f, a11 = 0.f;
#pragma unroll 4
    for (int i = 0; i < 32; i++) {
      const int k = (lane + i * 64) * 4;
      const float4 x0 = *(const float4*)(r0 + k);
      const float4 x1 = *(const float4*)(r1 + k);
      const float4 u0 = *(const float4*)(c0 + k);
      const float4 u1 = *(const float4*)(c1 + k);
      a00 += x0.x * u0.x + x0.y * u0.y + x0.z * u0.z + x0.w * u0.w;
      a01 += x0.x * u1.x + x0.y * u1.y + x0.z * u1.z + x0.w * u1.w;
      a10 += x1.x * u0.x + x1.y * u0.y + x1.z * u0.z + x1.w * u0.w;
      a11 += x1.x * u1.x + x1.y * u1.y + x1.z * u1.z + x1.w * u1.w;
    }
    a00 = wave_sum64(a00);
    a01 = wave_sum64(a01);
    a10 = wave_sum64(a10);
    a11 = wave_sum64(a11);
    if (lane == 0) {
      G[s0 * 100 + t0] = a00;             G[t0 * 100 + s0] = a00;
      G[s0 * 100 + t0 + 1] = a01;         G[(t0 + 1) * 100 + s0] = a01;
      G[(s0 + 1) * 100 + t0] = a10;       G[t0 * 100 + s0 + 1] = a10;
      G[(s0 + 1) * 100 + t0 + 1] = a11;   G[(t0 + 1) * 100 + s0 + 1] = a11;
    }
  } else if (wid < 1300) {
    const int t0 = (wid - 1275) * 4;
    const float* r0 = Ht + t0 * HH;
    const float* r1 = r0 + HH;
    const float* r2 = r1 + HH;
    const float* r3 = r2 + HH;
    float a0 = 0.f, a1 = 0.f, a2 = 0.f, a3 = 0.f;
#pragma unroll 4
    for (int i = 0; i < 32; i++) {
      const int k = (lane + i * 64) * 4;
      const float4 wv = *(const float4*)(w0 + k);
      const float4 x0 = *(const float4*)(r0 + k);
      const float4 x1 = *(const float4*)(r1 + k);
      const float4 x2 = *(const float4*)(r2 + k);
      const float4 x3 = *(const float4*)(r3 + k);
      a0 += x0.x * wv.x + x0.y * wv.y + x0.z * wv.z + x0.w * wv.w;
      a1 += x1.x * wv.x + x1.y * wv.y + x1.z * wv.z + x1.w * wv.w;
      a2 += x2.x * wv.x + x2.y * wv.y + x2.z * wv.z + x2.w * wv.w;
      a3 += x3.x * wv.x + x3.y * wv.y + x3.z * wv.z + x3.w * wv.w;
    }
    a0 = wave_sum64(a0);
    a1 = wave_sum64(a1);
    a2 = wave_sum64(a2);
    a3 = wave_sum64(a3);
    if (lane == 0) {
      y0[t0] = a0;
      y0[t0 + 1] = a1;
      y0[t0 + 2] = a2;
      y0[t0 + 3] = a3;
    }
  }
}

// ---------------- K3: sequential scalar solve for err_t (1 wave)
__global__ __launch_bounds__(64) void k3_solve(const float* __restrict__ G,
                                               const float* __restrict__ y0,
                                               const float* __restrict__ ytraj,
                                               float* __restrict__ errT) {
  __shared__ float Gs[100 * 101];  // stride 101 -> conflict-free column reads
  __shared__ float y0s[100];
  __shared__ float tgt[100];
  const int l = threadIdx.x;
  for (int idx = l; idx < 10000; idx += 64) {
    Gs[(idx / 100) * 101 + (idx % 100)] = G[idx];
  }
  if (l < 50) {
    y0s[l] = y0[l];       y0s[l + 50] = y0[l + 50];
    tgt[l] = ytraj[l];    tgt[l + 50] = ytraj[l + 50];
  }
  __syncthreads();
  float e_lo = 0.f, e_hi = 0.f;  // lane l holds err_l and err_{64+l}
  for (int t = 0; t < TT; t++) {
    float contrib = 0.f;
    if (l < t) contrib += e_lo * Gs[l * 101 + t];
    if (l + 64 < t) contrib += e_hi * Gs[(l + 64) * 101 + t];
    contrib = wave_sum64(contrib);
    const float err = tgt[t] - (y0s[t] + ILR * contrib);  // uniform across wave
    if (t < 64) {
      if (l == t) e_lo = err;
    } else {
      if (l == t - 64) e_hi = err;
    }
    if (l == 0) errT[t] = err;
  }
}

// ---------------- K4: per-column forward scan (c_t, w_f) + backward suffix-product
// 64-thread blocks x 128 -> spread across CUs (was 32 blocks, latency-bound)
__global__ __launch_bounds__(64) void k4_colscan(const float* __restrict__ Ht,
                                                 const float* __restrict__ errT,
                                                 const float* __restrict__ w0,
                                                 float* __restrict__ Ct,
                                                 float* __restrict__ wf) {
  __shared__ float es[100];
  const int tid = threadIdx.x;
  for (int i = tid; i < 100; i += 64) es[i] = errT[i];
  __syncthreads();
  const int j = blockIdx.x * 64 + tid;
  float w = w0[j];
#pragma unroll 4
  for (int t = 0; t < TT; t++) {
    const float h = Ht[t * HH + j];
    const float e = es[t];
    const float d = 1.f - h * h;
    w += ILR * e * h;                        // online update happens first
    Ct[t * HH + j] = ILR * d * (e - h * w);  // c_t
  }
  wf[j] = w;
  float prod = 1.f;  // suffix product of a_s = 1 - lr*h^2 over s>t
#pragma unroll 4
  for (int t = TT - 1; t >= 0; t--) {
    Ct[t * HH + j] *= prod;
    const float h = Ht[t * HH + j];
    prod *= (1.f - ILR * h * h);
  }
}

// ---------------- K5: e_i = Hrand[i]·w_f - y_rand[i]  (one block per i)
__global__ __launch_bounds__(256) void k5_pred(const float* __restrict__ Hr,
                                               const float* __restrict__ wf,
                                               const float* __restrict__ yr,
                                               float* __restrict__ e_r) {
  const int i = blockIdx.x;
  const int tid = threadIdx.x;
  const float* row = Hr + i * HH;
  float p = 0.f;
#pragma unroll
  for (int c = tid * 4; c < HH; c += 1024) {
    const float4 h4 = *(const float4*)(row + c);
    const float4 w4 = *(const float4*)(wf + c);
    p += h4.x * w4.x + h4.y * w4.y + h4.z * w4.z + h4.w * w4.w;
  }
  p = wave_sum64(p);
  __shared__ float ps[4];
  if ((tid & 63) == 0) ps[tid >> 6] = p;
  __syncthreads();
  if (tid == 0) {
    const float y = ps[0] + ps[1] + ps[2] + ps[3];
    e_r[i] = y - yr[i];
  }
}

// ---------------- K6: v_j, M rows (v*Ct in place; U), gb = colsum(M), loss
// 64-thread blocks x 128
__global__ __launch_bounds__(64) void k6_mbuild(const float* __restrict__ Hr,
                                                const float* __restrict__ e_r,
                                                const float* __restrict__ wf,
                                                float* __restrict__ Ct,
                                                float* __restrict__ U,
                                                float* __restrict__ gb_out,
                                                float* __restrict__ loss_out) {
  __shared__ float es[100];
  const int tid = threadIdx.x;
  for (int i = tid; i < 100; i += 64) es[i] = e_r[i];
  __syncthreads();
  if (blockIdx.x == 0) {  // block 0 (one wave): loss
    float s = es[tid] * es[tid];
    if (tid < 36) {
      const float q = es[tid + 64];
      s += q * q;
    }
    s = wave_sum64(s);
    if (tid == 0) loss_out[0] = s / (float)NN;
  }
  const int j = blockIdx.x * 64 + tid;
  const float wfj = wf[j];
  float v = 0.f;
#pragma unroll 4
  for (int i = 0; i < NN; i++) v += es[i] * Hr[i * HH + j];
  float gb = 0.f;
#pragma unroll 4
  for (int t = 0; t < TT; t++) {
    const float m = v * Ct[t * HH + j];
    Ct[t * HH + j] = m;
    gb += m;
  }
#pragma unroll 4
  for (int i = 0; i < NN; i++) {
    const float h = Hr[i * HH + j];
    const float m = es[i] * wfj * (1.f - h * h);
    U[i * HH + j] = m;
    gb += m;
  }
  gb_out[j] = gb;
}

// ---------------- K7: gW[m][j] = sum_k Xall[k][m] * Mmat[k][j]   (K=200)
__global__ __launch_bounds__(256) void k7_gw(const float* __restrict__ xt,
                                             const float* __restrict__ xr,
                                             const float* __restrict__ Mmat,
                                             float* __restrict__ gW) {
  __shared__ float As[16 * 64];  // [k][m]
  __shared__ float Bs[16 * 64];  // [k][j]
  const int tid = threadIdx.x;
  const int m0 = blockIdx.x * 64;
  const int col0 = blockIdx.y * 64;
  const int tx = tid & 15, ty = tid >> 4;
  const int lk = tid >> 4;         // 0..15
  const int lm4 = (tid & 15) * 4;  // 0..60
  float acc[4][4];
#pragma unroll
  for (int i = 0; i < 4; i++)
#pragma unroll
    for (int j = 0; j < 4; j++) acc[i][j] = 0.f;

  for (int k0 = 0; k0 < 208; k0 += 16) {
    const int gk = k0 + lk;
    float4 av, bv;
    if (gk < 200) {
      const float* asrc = (gk < TT) ? (xt + gk * DD) : (xr + (gk - TT) * DD);
      av = *(const float4*)(asrc + m0 + lm4);
      bv = *(const float4*)(Mmat + gk * HH + col0 + lm4);
    } else {
      av = make_float4(0.f, 0.f, 0.f, 0.f);
      bv = av;
    }
    __syncthreads();
    *(float4*)&As[lk * 64 + lm4] = av;
    *(float4*)&Bs[lk * 64 + lm4] = bv;
    __syncthreads();
#pragma unroll
    for (int k = 0; k < 16; k++) {
      const float4 a4 = *(const float4*)&As[k * 64 + ty * 4];
      const float4 b4 = *(const float4*)&Bs[k * 64 + tx * 4];
      const float a_[4] = {a4.x, a4.y, a4.z, a4.w};
      const float b_[4] = {b4.x, b4.y, b4.z, b4.w};
#pragma unroll
      for (int i = 0; i < 4; i++)
#pragma unroll
        for (int j = 0; j < 4; j++) acc[i][j] = fmaf(a_[i], b_[j], acc[i][j]);
    }
  }
  // gW base is d_out+1 (4B-aligned only) -> scalar stores
#pragma unroll
  for (int i = 0; i < 4; i++) {
    float* dst = gW + (m0 + ty * 4 + i) * HH + col0 + tx * 4;
    dst[0] = acc[i][0];
    dst[1] = acc[i][1];
    dst[2] = acc[i][2];
    dst[3] = acc[i][3];
  }
}

extern "C" void kernel_launch(void* const* d_in, const int* in_sizes, int n_in,
                              void* d_out, int out_size, void* d_ws, size_t ws_size,
                              hipStream_t stream) {
  (void)in_sizes; (void)n_in; (void)out_size; (void)ws_size;
  const float* xt = (const float*)d_in[0];   // [100,1024]
  const float* yt = (const float*)d_in[1];   // [100]
  const float* xr = (const float*)d_in[2];   // [100,1024]
  const float* yr = (const float*)d_in[3];   // [100]
  const float* W = (const float*)d_in[4];    // [1024,8192]
  const float* bias = (const float*)d_in[5]; // [8192]
  const float* w0 = (const float*)d_in[6];   // [8192]
  float* out = (float*)d_out;  // [0]=loss, [1..1+D*H)=gW, then gb[H]
  float* ws = (float*)d_ws;

  float* Hall = ws;              // 200*8192 (rows 0..99 Htraj, 100..199 Hrand)
  float* Ht = Hall;
  float* Hr = Hall + TT * HH;
  float* Ct = Hall + 200 * HH;   // 100*8192 -> becomes M rows 0..99
  float* U = Ct + TT * HH;       // 100*8192 -> M rows 100..199 (contiguous!)
  float* G = U + NN * HH;        // 100*100
  float* y0v = G + TT * TT;      // 100
  float* errT = y0v + TT;        // 100
  float* e_r = errT + TT;        // 100
  float* wf = e_r + NN;          // 8192

  k1_hidden2<<<512, 1024, 0, stream>>>(xt, xr, W, bias, Hall);
  k2_gram<<<325, 256, 0, stream>>>(Ht, w0, G, y0v);
  k3_solve<<<1, 64, 0, stream>>>(G, y0v, yt, errT);
  k4_colscan<<<HH / 64, 64, 0, stream>>>(Ht, errT, w0, Ct, wf);
  k5_pred<<<NN, 256, 0, stream>>>(Hr, wf, yr, e_r);
  k6_mbuild<<<HH / 64, 64, 0, stream>>>(Hr, e_r, wf, Ct, U, out + 1 + DD * HH, out);
  k7_gw<<<dim3(DD / 64, HH / 64), 256, 0, stream>>>(xt, xr, Ct, out + 1);
}

// Round 4
// 224.830 us; speedup vs baseline: 1.2336x; 1.0050x over previous
//
#include <hip/hip_runtime.h>
#include <math.h>

#define TT 100
#define NN 100
#define DD 1024
#define HH 8192
#define ILR 0.01f
#define XTP 200  // XT leading stride (floats)

__device__ __forceinline__ float wave_sum64(float v) {
#pragma unroll
  for (int off = 32; off; off >>= 1) v += __shfl_xor(v, off, 64);
  return v;
}

// ---------------- K0: XT[m][r] = Xall[r][m]  (tiled transpose, rows 0..199)
__global__ __launch_bounds__(256) void k0_xpose(const float* __restrict__ xt,
                                                const float* __restrict__ xr,
                                                float* __restrict__ XT) {
  __shared__ float tile[32][33];
  const int tx = threadIdx.x & 31;
  const int ty = threadIdx.x >> 5;  // 0..7
  const int m0 = blockIdx.x * 32;
  const int r0 = blockIdx.y * 32;
#pragma unroll
  for (int i = 0; i < 4; i++) {
    const int r = r0 + ty + i * 8;
    if (r < 200) {
      const float* src = (r < TT) ? (xt + r * DD) : (xr + (r - TT) * DD);
      tile[ty + i * 8][tx] = src[m0 + tx];
    }
  }
  __syncthreads();
#pragma unroll
  for (int i = 0; i < 4; i++) {
    const int r = r0 + tx;
    const int m = m0 + ty + i * 8;
    if (r < 200) XT[m * XTP + r] = tile[tx][ty + i * 8];
  }
}

// ---------------- K1: Hall = tanh(Xall @ W + b).
// 512 blocks x 512 threads; 8 k-groups of exactly 1 wave (K=128 each), private
// LDS staging per wave -> NO barriers in main loop. 8x8 register tiles.
// Block map: flat = m8 + 8*r + 32*chi, col-tile = chi*8+m8 -> the 4 row-tile
// siblings sharing a W column stripe are congruent mod 8 (same XCD heuristic).
__global__ __launch_bounds__(512, 4) void k1_hidden3(const float* __restrict__ XT,
                                                     const float* __restrict__ W,
                                                     const float* __restrict__ bias,
                                                     float* __restrict__ Hall) {
  __shared__ float smem[8 * 1088 + 8 * 1024];  // As[8][16*68] then Bs[8][16*64]
  const int tid = threadIdx.x;
  const int g = tid >> 6;   // k-group = wave 0..7
  const int t = tid & 63;   // lane
  const int flat = blockIdx.x;
  const int m8 = flat & 7;
  const int r_ = (flat >> 3) & 3;
  const int chi = flat >> 5;  // 0..15
  const int row0 = r_ * 64;
  const int col0 = (chi * 8 + m8) * 64;
  const int kbase = g * 128;
  float* As = smem + g * 1088;         // [16][68]
  float* Bs = smem + 8704 + g * 1024;  // [16][64]

  const int arow = (t & 7) * 8;   // this thread's 8 rows
  const int bcol = (t >> 3) * 8;  // this thread's 8 cols
  const int sk = t >> 2;          // staging k 0..15
  const int sq = (t & 3) * 16;    // staging quad offset

  float acc[8][8];
#pragma unroll
  for (int i = 0; i < 8; i++)
#pragma unroll
    for (int j = 0; j < 8; j++) acc[i][j] = 0.f;

  for (int k0 = 0; k0 < 128; k0 += 16) {
    // stage A from XT (pre-transposed): [k][row], no transpose needed
    {
      const float* src = XT + (kbase + k0 + sk) * XTP + row0 + sq;
      const float4 v0 = *(const float4*)(src + 0);
      const float4 v1 = *(const float4*)(src + 4);
      const float4 v2 = *(const float4*)(src + 8);
      const float4 v3 = *(const float4*)(src + 12);
      float* dst = As + sk * 68 + sq;
      *(float4*)(dst + 0) = v0;
      *(float4*)(dst + 4) = v1;
      *(float4*)(dst + 8) = v2;
      *(float4*)(dst + 12) = v3;
    }
    // stage B from W
    {
      const float* src = W + (kbase + k0 + sk) * HH + col0 + sq;
      const float4 v0 = *(const float4*)(src + 0);
      const float4 v1 = *(const float4*)(src + 4);
      const float4 v2 = *(const float4*)(src + 8);
      const float4 v3 = *(const float4*)(src + 12);
      float* dst = Bs + sk * 64 + sq;
      *(float4*)(dst + 0) = v0;
      *(float4*)(dst + 4) = v1;
      *(float4*)(dst + 8) = v2;
      *(float4*)(dst + 12) = v3;
    }
    // wave-internal ordering via lgkmcnt; no __syncthreads needed
#pragma unroll
    for (int k = 0; k < 16; k++) {
      const float4 a0 = *(const float4*)(As + k * 68 + arow);
      const float4 a1 = *(const float4*)(As + k * 68 + arow + 4);
      const float4 b0 = *(const float4*)(Bs + k * 64 + bcol);
      const float4 b1 = *(const float4*)(Bs + k * 64 + bcol + 4);
      const float a_[8] = {a0.x, a0.y, a0.z, a0.w, a1.x, a1.y, a1.z, a1.w};
      const float b_[8] = {b0.x, b0.y, b0.z, b0.w, b1.x, b1.y, b1.z, b1.w};
#pragma unroll
      for (int i = 0; i < 8; i++)
#pragma unroll
        for (int j = 0; j < 8; j++) acc[i][j] = fmaf(a_[i], b_[j], acc[i][j]);
    }
  }
  // combine 8 k-group partials in LDS (deterministic order), then tanh+store
  __syncthreads();
  float* Cs = smem;  // [64][64], aliases dead As region
  if (g == 0) {
#pragma unroll
    for (int i = 0; i < 8; i++) {
      *(float4*)(Cs + (arow + i) * 64 + bcol) =
          make_float4(acc[i][0], acc[i][1], acc[i][2], acc[i][3]);
      *(float4*)(Cs + (arow + i) * 64 + bcol + 4) =
          make_float4(acc[i][4], acc[i][5], acc[i][6], acc[i][7]);
    }
  }
  __syncthreads();
#pragma unroll
  for (int gg = 1; gg < 8; gg++) {
    if (g == gg) {
#pragma unroll
      for (int i = 0; i < 8; i++) {
        float* p = Cs + (arow + i) * 64 + bcol;
        float4 c0 = *(float4*)p;
        float4 c1 = *(float4*)(p + 4);
        c0.x += acc[i][0]; c0.y += acc[i][1]; c0.z += acc[i][2]; c0.w += acc[i][3];
        c1.x += acc[i][4]; c1.y += acc[i][5]; c1.z += acc[i][6]; c1.w += acc[i][7];
        *(float4*)p = c0;
        *(float4*)(p + 4) = c1;
      }
    }
    __syncthreads();
  }
  const int row = tid >> 3;         // 0..63
  const int cs = (tid & 7) * 8;     // 0..56
  if (row0 + row < 200) {
    const float4 c0 = *(const float4*)(Cs + row * 64 + cs);
    const float4 c1 = *(const float4*)(Cs + row * 64 + cs + 4);
    const float4 e0 = *(const float4*)(bias + col0 + cs);
    const float4 e1 = *(const float4*)(bias + col0 + cs + 4);
    float4 h0, h1;
    h0.x = tanhf(c0.x + e0.x); h0.y = tanhf(c0.y + e0.y);
    h0.z = tanhf(c0.z + e0.z); h0.w = tanhf(c0.w + e0.w);
    h1.x = tanhf(c1.x + e1.x); h1.y = tanhf(c1.y + e1.y);
    h1.z = tanhf(c1.z + e1.z); h1.w = tanhf(c1.w + e1.w);
    float* dst = Hall + (row0 + row) * HH + col0 + cs;
    *(float4*)dst = h0;
    *(float4*)(dst + 4) = h1;
  }
}

// ---------------- K2: G = Ht Ht^T via 4x4 row-group tiles + y0 = Ht w0
__global__ __launch_bounds__(256) void k2_gram4(const float* __restrict__ Ht,
                                                const float* __restrict__ w0,
                                                float* __restrict__ G,
                                                float* __restrict__ y0) {
  const int wid = blockIdx.x * 4 + (threadIdx.x >> 6);
  const int lane = threadIdx.x & 63;
  if (wid < 325) {  // pair (a<=b) of 25 row-groups of 4
    int a = 0, rem = wid;
    while (rem >= 25 - a) { rem -= 25 - a; a++; }
    const int b = a + rem;
    const float* Ra = Ht + (a * 4) * HH;
    const float* Rb = Ht + (b * 4) * HH;
    float acc[4][4];
#pragma unroll
    for (int r = 0; r < 4; r++)
#pragma unroll
      for (int c = 0; c < 4; c++) acc[r][c] = 0.f;
#pragma unroll 2
    for (int i = 0; i < 32; i++) {
      const int k = (lane + i * 64) * 4;
      float4 x[4], u[4];
#pragma unroll
      for (int r = 0; r < 4; r++) x[r] = *(const float4*)(Ra + r * HH + k);
#pragma unroll
      for (int c = 0; c < 4; c++) u[c] = *(const float4*)(Rb + c * HH + k);
#pragma unroll
      for (int r = 0; r < 4; r++)
#pragma unroll
        for (int c = 0; c < 4; c++) {
          acc[r][c] = fmaf(x[r].x, u[c].x, acc[r][c]);
          acc[r][c] = fmaf(x[r].y, u[c].y, acc[r][c]);
          acc[r][c] = fmaf(x[r].z, u[c].z, acc[r][c]);
          acc[r][c] = fmaf(x[r].w, u[c].w, acc[r][c]);
        }
    }
#pragma unroll
    for (int r = 0; r < 4; r++)
#pragma unroll
      for (int c = 0; c < 4; c++) acc[r][c] = wave_sum64(acc[r][c]);
    if (lane == 0) {
#pragma unroll
      for (int r = 0; r < 4; r++)
#pragma unroll
        for (int c = 0; c < 4; c++) {
          G[(a * 4 + r) * 100 + b * 4 + c] = acc[r][c];
          G[(b * 4 + c) * 100 + a * 4 + r] = acc[r][c];
        }
    }
  } else if (wid < 350) {  // y0 for row-group a
    const int a = wid - 325;
    const float* R = Ht + (a * 4) * HH;
    float acc[4] = {0.f, 0.f, 0.f, 0.f};
#pragma unroll 2
    for (int i = 0; i < 32; i++) {
      const int k = (lane + i * 64) * 4;
      const float4 wv = *(const float4*)(w0 + k);
#pragma unroll
      for (int r = 0; r < 4; r++) {
        const float4 x = *(const float4*)(R + r * HH + k);
        acc[r] += x.x * wv.x + x.y * wv.y + x.z * wv.z + x.w * wv.w;
      }
    }
#pragma unroll
    for (int r = 0; r < 4; r++) acc[r] = wave_sum64(acc[r]);
    if (lane == 0) {
#pragma unroll
      for (int r = 0; r < 4; r++) y0[a * 4 + r] = acc[r];
    }
  }
}

// ---------------- K3: sequential scalar solve for err_t (1 wave)
__global__ __launch_bounds__(64) void k3_solve(const float* __restrict__ G,
                                               const float* __restrict__ y0,
                                               const float* __restrict__ ytraj,
                                               float* __restrict__ errT) {
  __shared__ float Gs[100 * 101];
  __shared__ float y0s[100];
  __shared__ float tgt[100];
  const int l = threadIdx.x;
  for (int idx = l; idx < 10000; idx += 64) {
    Gs[(idx / 100) * 101 + (idx % 100)] = G[idx];
  }
  if (l < 50) {
    y0s[l] = y0[l];       y0s[l + 50] = y0[l + 50];
    tgt[l] = ytraj[l];    tgt[l + 50] = ytraj[l + 50];
  }
  __syncthreads();
  float e_lo = 0.f, e_hi = 0.f;
  for (int t = 0; t < TT; t++) {
    float contrib = 0.f;
    if (l < t) contrib += e_lo * Gs[l * 101 + t];
    if (l + 64 < t) contrib += e_hi * Gs[(l + 64) * 101 + t];
    contrib = wave_sum64(contrib);
    const float err = tgt[t] - (y0s[t] + ILR * contrib);
    if (t < 64) {
      if (l == t) e_lo = err;
    } else {
      if (l == t - 64) e_hi = err;
    }
    if (l == 0) errT[t] = err;
  }
}

// ---------------- K4: per-column forward scan (c_t, w_f) + backward suffix-product
__global__ __launch_bounds__(64) void k4_colscan(const float* __restrict__ Ht,
                                                 const float* __restrict__ errT,
                                                 const float* __restrict__ w0,
                                                 float* __restrict__ Ct,
                                                 float* __restrict__ wf) {
  __shared__ float es[100];
  const int tid = threadIdx.x;
  for (int i = tid; i < 100; i += 64) es[i] = errT[i];
  __syncthreads();
  const int j = blockIdx.x * 64 + tid;
  float w = w0[j];
#pragma unroll 4
  for (int t = 0; t < TT; t++) {
    const float h = Ht[t * HH + j];
    const float e = es[t];
    const float d = 1.f - h * h;
    w += ILR * e * h;
    Ct[t * HH + j] = ILR * d * (e - h * w);
  }
  wf[j] = w;
  float prod = 1.f;
#pragma unroll 4
  for (int t = TT - 1; t >= 0; t--) {
    Ct[t * HH + j] *= prod;
    const float h = Ht[t * HH + j];
    prod *= (1.f - ILR * h * h);
  }
}

// ---------------- K5: e_i = Hrand[i]·w_f - y_rand[i]
__global__ __launch_bounds__(256) void k5_pred(const float* __restrict__ Hr,
                                               const float* __restrict__ wf,
                                               const float* __restrict__ yr,
                                               float* __restrict__ e_r) {
  const int i = blockIdx.x;
  const int tid = threadIdx.x;
  const float* row = Hr + i * HH;
  float p = 0.f;
#pragma unroll
  for (int c = tid * 4; c < HH; c += 1024) {
    const float4 h4 = *(const float4*)(row + c);
    const float4 w4 = *(const float4*)(wf + c);
    p += h4.x * w4.x + h4.y * w4.y + h4.z * w4.z + h4.w * w4.w;
  }
  p = wave_sum64(p);
  __shared__ float ps[4];
  if ((tid & 63) == 0) ps[tid >> 6] = p;
  __syncthreads();
  if (tid == 0) {
    const float y = ps[0] + ps[1] + ps[2] + ps[3];
    e_r[i] = y - yr[i];
  }
}

// ---------------- K6: v_j, M rows (v*Ct in place; U), gb = colsum(M), loss
__global__ __launch_bounds__(64) void k6_mbuild(const float* __restrict__ Hr,
                                                const float* __restrict__ e_r,
                                                const float* __restrict__ wf,
                                                float* __restrict__ Ct,
                                                float* __restrict__ U,
                                                float* __restrict__ gb_out,
                                                float* __restrict__ loss_out) {
  __shared__ float es[100];
  const int tid = threadIdx.x;
  for (int i = tid; i < 100; i += 64) es[i] = e_r[i];
  __syncthreads();
  if (blockIdx.x == 0) {
    float s = es[tid] * es[tid];
    if (tid < 36) {
      const float q = es[tid + 64];
      s += q * q;
    }
    s = wave_sum64(s);
    if (tid == 0) loss_out[0] = s / (float)NN;
  }
  const int j = blockIdx.x * 64 + tid;
  const float wfj = wf[j];
  float v = 0.f;
#pragma unroll 4
  for (int i = 0; i < NN; i++) v += es[i] * Hr[i * HH + j];
  float gb = 0.f;
#pragma unroll 4
  for (int t = 0; t < TT; t++) {
    const float m = v * Ct[t * HH + j];
    Ct[t * HH + j] = m;
    gb += m;
  }
#pragma unroll 4
  for (int i = 0; i < NN; i++) {
    const float h = Hr[i * HH + j];
    const float m = es[i] * wfj * (1.f - h * h);
    U[i * HH + j] = m;
    gb += m;
  }
  gb_out[j] = gb;
}

// ---------------- K7: gW[m][j] = sum_k Xall[k][m]*Mmat[k][j], K=200 (pad 208)
// 128x128 tile, 256 threads, 8x8 per thread. A octets get a 4-float gap every
// 4 octets so the 16-octet b128 reads are <=2-way bank-aliased.
__device__ __forceinline__ int agap(int oct) { return oct * 8 + (oct >> 2) * 4; }

__global__ __launch_bounds__(256, 2) void k7_gw2(const float* __restrict__ xt,
                                                 const float* __restrict__ xr,
                                                 const float* __restrict__ Mmat,
                                                 float* __restrict__ gW) {
  __shared__ float As[16 * 144];  // [k][m-with-gaps]
  __shared__ float Bs[16 * 128];  // [k][j]
  const int tid = threadIdx.x;
  const int m0 = blockIdx.x * 128;
  const int col0 = blockIdx.y * 128;
  const int moct = tid & 15;   // this thread's m octet
  const int noct = tid >> 4;   // this thread's n octet
  const int sk = tid >> 4;     // staging k 0..15
  const int soct = tid & 15;   // staging octet

  float acc[8][8];
#pragma unroll
  for (int i = 0; i < 8; i++)
#pragma unroll
    for (int j = 0; j < 8; j++) acc[i][j] = 0.f;

  for (int k0 = 0; k0 < 208; k0 += 16) {
    const int gk = k0 + sk;
    float4 a0, a1, b0, b1;
    if (gk < 200) {
      const float* asrc = (gk < TT) ? (xt + gk * DD) : (xr + (gk - TT) * DD);
      a0 = *(const float4*)(asrc + m0 + soct * 8);
      a1 = *(const float4*)(asrc + m0 + soct * 8 + 4);
      b0 = *(const float4*)(Mmat + gk * HH + col0 + soct * 8);
      b1 = *(const float4*)(Mmat + gk * HH + col0 + soct * 8 + 4);
    } else {
      a0 = make_float4(0.f, 0.f, 0.f, 0.f);
      a1 = a0; b0 = a0; b1 = a0;
    }
    __syncthreads();
    {
      float* ad = As + sk * 144 + agap(soct);
      *(float4*)ad = a0;
      *(float4*)(ad + 4) = a1;
      float* bd = Bs + sk * 128 + soct * 8;
      *(float4*)bd = b0;
      *(float4*)(bd + 4) = b1;
    }
    __syncthreads();
#pragma unroll
    for (int k = 0; k < 16; k++) {
      const float4 a0_ = *(const float4*)(As + k * 144 + agap(moct));
      const float4 a1_ = *(const float4*)(As + k * 144 + agap(moct) + 4);
      const float4 b0_ = *(const float4*)(Bs + k * 128 + noct * 8);
      const float4 b1_ = *(const float4*)(Bs + k * 128 + noct * 8 + 4);
      const float a_[8] = {a0_.x, a0_.y, a0_.z, a0_.w, a1_.x, a1_.y, a1_.z, a1_.w};
      const float b_[8] = {b0_.x, b0_.y, b0_.z, b0_.w, b1_.x, b1_.y, b1_.z, b1_.w};
#pragma unroll
      for (int i = 0; i < 8; i++)
#pragma unroll
        for (int j = 0; j < 8; j++) acc[i][j] = fmaf(a_[i], b_[j], acc[i][j]);
    }
  }
  // gW base misaligned (d_out+1) -> scalar stores
#pragma unroll
  for (int i = 0; i < 8; i++) {
    float* dst = gW + (m0 + moct * 8 + i) * HH + col0 + noct * 8;
#pragma unroll
    for (int j = 0; j < 8; j++) dst[j] = acc[i][j];
  }
}

extern "C" void kernel_launch(void* const* d_in, const int* in_sizes, int n_in,
                              void* d_out, int out_size, void* d_ws, size_t ws_size,
                              hipStream_t stream) {
  (void)in_sizes; (void)n_in; (void)out_size; (void)ws_size;
  const float* xt = (const float*)d_in[0];   // [100,1024]
  const float* yt = (const float*)d_in[1];   // [100]
  const float* xr = (const float*)d_in[2];   // [100,1024]
  const float* yr = (const float*)d_in[3];   // [100]
  const float* W = (const float*)d_in[4];    // [1024,8192]
  const float* bias = (const float*)d_in[5]; // [8192]
  const float* w0 = (const float*)d_in[6];   // [8192]
  float* out = (float*)d_out;  // [0]=loss, [1..1+D*H)=gW, then gb[H]
  float* ws = (float*)d_ws;

  float* Hall = ws;              // 200*8192
  float* Ht = Hall;
  float* Hr = Hall + TT * HH;
  float* Ct = Hall + 200 * HH;   // 100*8192 -> M rows 0..99
  float* U = Ct + TT * HH;       // 100*8192 -> M rows 100..199
  float* XT = U;                 // alias: XT (1024x200) dead before k6 writes U
  float* G = U + NN * HH;        // 100*100
  float* y0v = G + TT * TT;      // 100
  float* errT = y0v + TT;        // 100
  float* e_r = errT + TT;        // 100
  float* wf = e_r + NN;          // 8192

  k0_xpose<<<dim3(32, 7), 256, 0, stream>>>(xt, xr, XT);
  k1_hidden3<<<512, 512, 0, stream>>>(XT, W, bias, Hall);
  k2_gram4<<<88, 256, 0, stream>>>(Ht, w0, G, y0v);
  k3_solve<<<1, 64, 0, stream>>>(G, y0v, yt, errT);
  k4_colscan<<<HH / 64, 64, 0, stream>>>(Ht, errT, w0, Ct, wf);
  k5_pred<<<NN, 256, 0, stream>>>(Hr, wf, yr, e_r);
  k6_mbuild<<<HH / 64, 64, 0, stream>>>(Hr, e_r, wf, Ct, U, out + 1 + DD * HH, out);
  k7_gw2<<<dim3(8, 64), 256, 0, stream>>>(xt, xr, Ct, out + 1);
}

// Round 6
// 193.692 us; speedup vs baseline: 1.4319x; 1.1608x over previous
//
#include <hip/hip_runtime.h>
#include <math.h>

#define TT 100
#define NN 100
#define DD 1024
#define HH 8192
#define ILR 0.01f
#define XTP 256  // XT leading stride (floats); rows 200..255 zero-padded

__device__ __forceinline__ float wave_sum64(float v) {
#pragma unroll
  for (int off = 32; off; off >>= 1) v += __shfl_xor(v, off, 64);
  return v;
}

// gap map for 64-col rows (stride 68): octet o -> o*8 + 4 if o>=4.
// Starts {0,8,16,24,36,44,52,60} mod 32 = {0,8,16,24,4,12,20,28} all distinct.
__device__ __forceinline__ int gmap(int c) { return c + ((c >> 5) << 2); }
// gap map for 128-col rows (stride 144): octet o -> o*8 + (o>>2)*4.
// Starts mod 32 = {0,8,16,24,4,12,20,28,...} repeating; max = 132+8 = 140 <= 144.
__device__ __forceinline__ int agap(int oct) { return oct * 8 + (oct >> 2) * 4; }

// ---------------- K0: XT[m][r] = Xall[r][m]; rows 200..255 zeroed.
__global__ __launch_bounds__(256) void k0_xpose(const float* __restrict__ xt,
                                                const float* __restrict__ xr,
                                                float* __restrict__ XT) {
  __shared__ float tile[32][33];
  const int tx = threadIdx.x & 31;
  const int ty = threadIdx.x >> 5;  // 0..7
  const int m0 = blockIdx.x * 32;
  const int r0 = blockIdx.y * 32;
#pragma unroll
  for (int i = 0; i < 4; i++) {
    const int r = r0 + ty + i * 8;
    if (r < 200) {
      const float* src = (r < TT) ? (xt + r * DD) : (xr + (r - TT) * DD);
      tile[ty + i * 8][tx] = src[m0 + tx];
    }
  }
  __syncthreads();
#pragma unroll
  for (int i = 0; i < 4; i++) {
    const int r = r0 + tx;  // < 256
    const int m = m0 + ty + i * 8;
    XT[m * XTP + r] = (r < 200) ? tile[tx][ty + i * 8] : 0.f;
  }
}

// ---------------- K1: Hall = tanh(Xall @ W + b).
// 512 blocks x 512 threads; 8 k-groups of 1 wave (K=128 each), private gapped
// LDS staging (34.8KB), no barriers in main loop, 8x8 register tiles.
__global__ __launch_bounds__(512, 4) void k1_hidden5(const float* __restrict__ XT,
                                                     const float* __restrict__ W,
                                                     const float* __restrict__ bias,
                                                     float* __restrict__ Hall) {
  __shared__ float smem[8 * 1088];  // per group: As[8][68] + Bs[8][68]
  const int tid = threadIdx.x;
  const int g = tid >> 6;   // wave / k-group
  const int t = tid & 63;   // lane
  const int flat = blockIdx.x;
  const int m8 = flat & 7;
  const int r_ = (flat >> 3) & 3;
  const int chi = flat >> 5;  // 0..15
  const int row0 = r_ * 64;
  const int col0 = (chi * 8 + m8) * 64;
  const int kbase = g * 128;
  float* As = smem + g * 1088;  // [8][68] gapped
  float* Bs = As + 544;         // [8][68] gapped

  const int arow = (t & 7) * 8;   // this thread's 8 rows
  const int bcol = (t >> 3) * 8;  // this thread's 8 cols
  const int ra = gmap(arow);
  const int rb = gmap(bcol);
  const int sk = t >> 3;          // staging k-row 0..7
  const int c0 = (t & 7) * 4;     // staging quad col (0..28)
  const int w0_ = c0;             // gmap(c0), c0<32
  const int w1_ = c0 + 36;        // gmap(c0+32)

  float acc[8][8];
#pragma unroll
  for (int i = 0; i < 8; i++)
#pragma unroll
    for (int j = 0; j < 8; j++) acc[i][j] = 0.f;

#pragma unroll 1
  for (int ch = 0; ch < 16; ch++) {
    const int kk = kbase + ch * 8 + sk;
    const float4 a0 = *(const float4*)(XT + kk * XTP + row0 + c0);
    const float4 a1 = *(const float4*)(XT + kk * XTP + row0 + c0 + 32);
    const float4 b0 = *(const float4*)(W + kk * HH + col0 + c0);
    const float4 b1 = *(const float4*)(W + kk * HH + col0 + c0 + 32);
    *(float4*)(As + sk * 68 + w0_) = a0;
    *(float4*)(As + sk * 68 + w1_) = a1;
    *(float4*)(Bs + sk * 68 + w0_) = b0;
    *(float4*)(Bs + sk * 68 + w1_) = b1;
    // wave-private staging: DS ops in-order per wave, no barrier needed
#pragma unroll
    for (int k = 0; k < 8; k++) {
      const float4 a0_ = *(const float4*)(As + k * 68 + ra);
      const float4 a1_ = *(const float4*)(As + k * 68 + ra + 4);
      const float4 b0_ = *(const float4*)(Bs + k * 68 + rb);
      const float4 b1_ = *(const float4*)(Bs + k * 68 + rb + 4);
      const float a_[8] = {a0_.x, a0_.y, a0_.z, a0_.w, a1_.x, a1_.y, a1_.z, a1_.w};
      const float b_[8] = {b0_.x, b0_.y, b0_.z, b0_.w, b1_.x, b1_.y, b1_.z, b1_.w};
#pragma unroll
      for (int i = 0; i < 8; i++)
#pragma unroll
        for (int j = 0; j < 8; j++) acc[i][j] = fmaf(a_[i], b_[j], acc[i][j]);
    }
  }
  // combine 8 k-group partials in LDS (deterministic order), then tanh+store
  __syncthreads();
  float* Cs = smem;  // [64][68] = 4352 floats, aliases groups 0-3 staging (dead)
  if (g == 0) {
#pragma unroll
    for (int i = 0; i < 8; i++) {
      *(float4*)(Cs + (arow + i) * 68 + bcol) =
          make_float4(acc[i][0], acc[i][1], acc[i][2], acc[i][3]);
      *(float4*)(Cs + (arow + i) * 68 + bcol + 4) =
          make_float4(acc[i][4], acc[i][5], acc[i][6], acc[i][7]);
    }
  }
  __syncthreads();
#pragma unroll 1
  for (int gg = 1; gg < 8; gg++) {
    if (g == gg) {
#pragma unroll
      for (int i = 0; i < 8; i++) {
        float* p = Cs + (arow + i) * 68 + bcol;
        float4 v0 = *(float4*)p;
        float4 v1 = *(float4*)(p + 4);
        v0.x += acc[i][0]; v0.y += acc[i][1]; v0.z += acc[i][2]; v0.w += acc[i][3];
        v1.x += acc[i][4]; v1.y += acc[i][5]; v1.z += acc[i][6]; v1.w += acc[i][7];
        *(float4*)p = v0;
        *(float4*)(p + 4) = v1;
      }
    }
    __syncthreads();
  }
  const int row = tid >> 3;      // 0..63
  const int cs = (tid & 7) * 8;  // 0..56
  if (row0 + row < 200) {
    const float4 c0v = *(const float4*)(Cs + row * 68 + cs);
    const float4 c1v = *(const float4*)(Cs + row * 68 + cs + 4);
    const float4 e0 = *(const float4*)(bias + col0 + cs);
    const float4 e1 = *(const float4*)(bias + col0 + cs + 4);
    float4 h0, h1;
    h0.x = tanhf(c0v.x + e0.x); h0.y = tanhf(c0v.y + e0.y);
    h0.z = tanhf(c0v.z + e0.z); h0.w = tanhf(c0v.w + e0.w);
    h1.x = tanhf(c1v.x + e1.x); h1.y = tanhf(c1v.y + e1.y);
    h1.z = tanhf(c1v.z + e1.z); h1.w = tanhf(c1v.w + e1.w);
    float* dst = Hall + (row0 + row) * HH + col0 + cs;
    *(float4*)dst = h0;
    *(float4*)(dst + 4) = h1;
  }
}

// ---------------- K2: G = Ht Ht^T via 4x4 row-group tiles + y0 = Ht w0
__global__ __launch_bounds__(256) void k2_gram4(const float* __restrict__ Ht,
                                                const float* __restrict__ w0,
                                                float* __restrict__ G,
                                                float* __restrict__ y0) {
  const int wid = blockIdx.x * 4 + (threadIdx.x >> 6);
  const int lane = threadIdx.x & 63;
  if (wid < 325) {  // pair (a<=b) of 25 row-groups of 4
    int a = 0, rem = wid;
    while (rem >= 25 - a) { rem -= 25 - a; a++; }
    const int b = a + rem;
    const float* Ra = Ht + (a * 4) * HH;
    const float* Rb = Ht + (b * 4) * HH;
    float acc[4][4];
#pragma unroll
    for (int r = 0; r < 4; r++)
#pragma unroll
      for (int c = 0; c < 4; c++) acc[r][c] = 0.f;
#pragma unroll 2
    for (int i = 0; i < 32; i++) {
      const int k = (lane + i * 64) * 4;
      float4 x[4], u[4];
#pragma unroll
      for (int r = 0; r < 4; r++) x[r] = *(const float4*)(Ra + r * HH + k);
#pragma unroll
      for (int c = 0; c < 4; c++) u[c] = *(const float4*)(Rb + c * HH + k);
#pragma unroll
      for (int r = 0; r < 4; r++)
#pragma unroll
        for (int c = 0; c < 4; c++) {
          acc[r][c] = fmaf(x[r].x, u[c].x, acc[r][c]);
          acc[r][c] = fmaf(x[r].y, u[c].y, acc[r][c]);
          acc[r][c] = fmaf(x[r].z, u[c].z, acc[r][c]);
          acc[r][c] = fmaf(x[r].w, u[c].w, acc[r][c]);
        }
    }
#pragma unroll
    for (int r = 0; r < 4; r++)
#pragma unroll
      for (int c = 0; c < 4; c++) acc[r][c] = wave_sum64(acc[r][c]);
    if (lane == 0) {
#pragma unroll
      for (int r = 0; r < 4; r++)
#pragma unroll
        for (int c = 0; c < 4; c++) {
          G[(a * 4 + r) * 100 + b * 4 + c] = acc[r][c];
          G[(b * 4 + c) * 100 + a * 4 + r] = acc[r][c];
        }
    }
  } else if (wid < 350) {  // y0 for row-group a
    const int a = wid - 325;
    const float* R = Ht + (a * 4) * HH;
    float acc[4] = {0.f, 0.f, 0.f, 0.f};
#pragma unroll 2
    for (int i = 0; i < 32; i++) {
      const int k = (lane + i * 64) * 4;
      const float4 wv = *(const float4*)(w0 + k);
#pragma unroll
      for (int r = 0; r < 4; r++) {
        const float4 x = *(const float4*)(R + r * HH + k);
        acc[r] += x.x * wv.x + x.y * wv.y + x.z * wv.z + x.w * wv.w;
      }
    }
#pragma unroll
    for (int r = 0; r < 4; r++) acc[r] = wave_sum64(acc[r]);
    if (lane == 0) {
#pragma unroll
      for (int r = 0; r < 4; r++) y0[a * 4 + r] = acc[r];
    }
  }
}

// ---------------- K3: sequential scalar solve for err_t (1 wave)
__global__ __launch_bounds__(64) void k3_solve(const float* __restrict__ G,
                                               const float* __restrict__ y0,
                                               const float* __restrict__ ytraj,
                                               float* __restrict__ errT) {
  __shared__ float Gs[100 * 101];
  __shared__ float y0s[100];
  __shared__ float tgt[100];
  const int l = threadIdx.x;
  for (int idx = l; idx < 10000; idx += 64) {
    Gs[(idx / 100) * 101 + (idx % 100)] = G[idx];
  }
  if (l < 50) {
    y0s[l] = y0[l];       y0s[l + 50] = y0[l + 50];
    tgt[l] = ytraj[l];    tgt[l + 50] = ytraj[l + 50];
  }
  __syncthreads();
  float e_lo = 0.f, e_hi = 0.f;
  for (int t = 0; t < TT; t++) {
    float contrib = 0.f;
    if (l < t) contrib += e_lo * Gs[l * 101 + t];
    if (l + 64 < t) contrib += e_hi * Gs[(l + 64) * 101 + t];
    contrib = wave_sum64(contrib);
    const float err = tgt[t] - (y0s[t] + ILR * contrib);
    if (t < 64) {
      if (l == t) e_lo = err;
    } else {
      if (l == t - 64) e_hi = err;
    }
    if (l == 0) errT[t] = err;
  }
}

// ---------------- K4: per-column forward scan (c_t, w_f) + backward suffix-
// product. Loads batched in groups of 10 (independent) to hide latency.
__global__ __launch_bounds__(64) void k4_colscan(const float* __restrict__ Ht,
                                                 const float* __restrict__ errT,
                                                 const float* __restrict__ w0,
                                                 float* __restrict__ Ct,
                                                 float* __restrict__ wf) {
  __shared__ float es[100];
  const int tid = threadIdx.x;
  for (int i = tid; i < 100; i += 64) es[i] = errT[i];
  __syncthreads();
  const int j = blockIdx.x * 64 + tid;
  float w = w0[j];
#pragma unroll 1
  for (int tc = 0; tc < TT; tc += 10) {
    float h[10];
#pragma unroll
    for (int u = 0; u < 10; u++) h[u] = Ht[(tc + u) * HH + j];
#pragma unroll
    for (int u = 0; u < 10; u++) {
      const float e = es[tc + u];
      const float d = 1.f - h[u] * h[u];
      w += ILR * e * h[u];
      Ct[(tc + u) * HH + j] = ILR * d * (e - h[u] * w);
    }
  }
  wf[j] = w;
  float prod = 1.f;
#pragma unroll 1
  for (int tc = TT - 10; tc >= 0; tc -= 10) {
    float h[10], ct[10];
#pragma unroll
    for (int u = 9; u >= 0; u--) {
      h[u] = Ht[(tc + u) * HH + j];
      ct[u] = Ct[(tc + u) * HH + j];
    }
#pragma unroll
    for (int u = 9; u >= 0; u--) {
      Ct[(tc + u) * HH + j] = ct[u] * prod;
      prod *= (1.f - ILR * h[u] * h[u]);
    }
  }
}

// ---------------- K5: e_i = Hrand[i]·w_f - y_rand[i]
__global__ __launch_bounds__(256) void k5_pred(const float* __restrict__ Hr,
                                               const float* __restrict__ wf,
                                               const float* __restrict__ yr,
                                               float* __restrict__ e_r) {
  const int i = blockIdx.x;
  const int tid = threadIdx.x;
  const float* row = Hr + i * HH;
  float p = 0.f;
#pragma unroll
  for (int c = tid * 4; c < HH; c += 1024) {
    const float4 h4 = *(const float4*)(row + c);
    const float4 w4 = *(const float4*)(wf + c);
    p += h4.x * w4.x + h4.y * w4.y + h4.z * w4.z + h4.w * w4.w;
  }
  p = wave_sum64(p);
  __shared__ float ps[4];
  if ((tid & 63) == 0) ps[tid >> 6] = p;
  __syncthreads();
  if (tid == 0) {
    const float y = ps[0] + ps[1] + ps[2] + ps[3];
    e_r[i] = y - yr[i];
  }
}

// ---------------- K6: v_j, M rows (v*Ct in place; U), gb = colsum(M), loss
__global__ __launch_bounds__(64) void k6_mbuild(const float* __restrict__ Hr,
                                                const float* __restrict__ e_r,
                                                const float* __restrict__ wf,
                                                float* __restrict__ Ct,
                                                float* __restrict__ U,
                                                float* __restrict__ gb_out,
                                                float* __restrict__ loss_out) {
  __shared__ float es[100];
  const int tid = threadIdx.x;
  for (int i = tid; i < 100; i += 64) es[i] = e_r[i];
  __syncthreads();
  if (blockIdx.x == 0) {
    float s = es[tid] * es[tid];
    if (tid < 36) {
      const float q = es[tid + 64];
      s += q * q;
    }
    s = wave_sum64(s);
    if (tid == 0) loss_out[0] = s / (float)NN;
  }
  const int j = blockIdx.x * 64 + tid;
  const float wfj = wf[j];
  float v = 0.f;
#pragma unroll 1
  for (int ic = 0; ic < NN; ic += 10) {
    float h[10];
#pragma unroll
    for (int u = 0; u < 10; u++) h[u] = Hr[(ic + u) * HH + j];
#pragma unroll
    for (int u = 0; u < 10; u++) v += es[ic + u] * h[u];
  }
  float gb = 0.f;
#pragma unroll 1
  for (int tc = 0; tc < TT; tc += 10) {
    float ct[10];
#pragma unroll
    for (int u = 0; u < 10; u++) ct[u] = Ct[(tc + u) * HH + j];
#pragma unroll
    for (int u = 0; u < 10; u++) {
      const float m = v * ct[u];
      Ct[(tc + u) * HH + j] = m;
      gb += m;
    }
  }
#pragma unroll 1
  for (int ic = 0; ic < NN; ic += 10) {
    float h[10];
#pragma unroll
    for (int u = 0; u < 10; u++) h[u] = Hr[(ic + u) * HH + j];
#pragma unroll
    for (int u = 0; u < 10; u++) {
      const float m = es[ic + u] * wfj * (1.f - h[u] * h[u]);
      U[(ic + u) * HH + j] = m;
      gb += m;
    }
  }
  gb_out[j] = gb;
}

// ---------------- K7: gW[m][j] = sum_k Xall[k][m]*Mmat[k][j], K=200 (pad 208)
// 128x128 tile, 256 threads, 8x8 per thread, agap LDS rows (stride 144,
// max offset 140 <= 144 -- proven in-round-4 layout).
__global__ __launch_bounds__(256, 2) void k7_gw4(const float* __restrict__ xt,
                                                 const float* __restrict__ xr,
                                                 const float* __restrict__ Mmat,
                                                 float* __restrict__ gW) {
  __shared__ float As[16 * 144];  // [k][m gapped]
  __shared__ float Bs[16 * 144];  // [k][j gapped]
  const int tid = threadIdx.x;
  const int m0 = blockIdx.x * 128;
  const int col0 = blockIdx.y * 128;
  const int moct = tid & 15;   // thread m octet
  const int noct = tid >> 4;   // thread n octet
  const int rm = agap(moct);
  const int rn = agap(noct);
  const int sk = tid >> 4;     // staging k 0..15
  const int soct = tid & 15;   // staging octet
  const int sw = agap(soct);

  float acc[8][8];
#pragma unroll
  for (int i = 0; i < 8; i++)
#pragma unroll
    for (int j = 0; j < 8; j++) acc[i][j] = 0.f;

#pragma unroll 1
  for (int k0 = 0; k0 < 208; k0 += 16) {
    const int gk = k0 + sk;
    float4 a0, a1, b0, b1;
    if (gk < 200) {
      const float* asrc = (gk < TT) ? (xt + gk * DD) : (xr + (gk - TT) * DD);
      a0 = *(const float4*)(asrc + m0 + soct * 8);
      a1 = *(const float4*)(asrc + m0 + soct * 8 + 4);
      b0 = *(const float4*)(Mmat + gk * HH + col0 + soct * 8);
      b1 = *(const float4*)(Mmat + gk * HH + col0 + soct * 8 + 4);
    } else {
      a0 = make_float4(0.f, 0.f, 0.f, 0.f);
      a1 = a0; b0 = a0; b1 = a0;
    }
    __syncthreads();
    *(float4*)(As + sk * 144 + sw) = a0;
    *(float4*)(As + sk * 144 + sw + 4) = a1;
    *(float4*)(Bs + sk * 144 + sw) = b0;
    *(float4*)(Bs + sk * 144 + sw + 4) = b1;
    __syncthreads();
#pragma unroll
    for (int k = 0; k < 16; k++) {
      const float4 a0_ = *(const float4*)(As + k * 144 + rm);
      const float4 a1_ = *(const float4*)(As + k * 144 + rm + 4);
      const float4 b0_ = *(const float4*)(Bs + k * 144 + rn);
      const float4 b1_ = *(const float4*)(Bs + k * 144 + rn + 4);
      const float a_[8] = {a0_.x, a0_.y, a0_.z, a0_.w, a1_.x, a1_.y, a1_.z, a1_.w};
      const float b_[8] = {b0_.x, b0_.y, b0_.z, b0_.w, b1_.x, b1_.y, b1_.z, b1_.w};
#pragma unroll
      for (int i = 0; i < 8; i++)
#pragma unroll
        for (int j = 0; j < 8; j++) acc[i][j] = fmaf(a_[i], b_[j], acc[i][j]);
    }
  }
  // gW base misaligned (d_out+1) -> scalar stores
#pragma unroll
  for (int i = 0; i < 8; i++) {
    float* dst = gW + (m0 + moct * 8 + i) * HH + col0 + noct * 8;
#pragma unroll
    for (int j = 0; j < 8; j++) dst[j] = acc[i][j];
  }
}

extern "C" void kernel_launch(void* const* d_in, const int* in_sizes, int n_in,
                              void* d_out, int out_size, void* d_ws, size_t ws_size,
                              hipStream_t stream) {
  (void)in_sizes; (void)n_in; (void)out_size; (void)ws_size;
  const float* xt = (const float*)d_in[0];   // [100,1024]
  const float* yt = (const float*)d_in[1];   // [100]
  const float* xr = (const float*)d_in[2];   // [100,1024]
  const float* yr = (const float*)d_in[3];   // [100]
  const float* W = (const float*)d_in[4];    // [1024,8192]
  const float* bias = (const float*)d_in[5]; // [8192]
  const float* w0 = (const float*)d_in[6];   // [8192]
  float* out = (float*)d_out;  // [0]=loss, [1..1+D*H)=gW, then gb[H]
  float* ws = (float*)d_ws;

  float* Hall = ws;              // 200*8192
  float* Ht = Hall;
  float* Hr = Hall + TT * HH;
  float* Ct = Hall + 200 * HH;   // 100*8192 -> M rows 0..99
  float* U = Ct + TT * HH;       // 100*8192 -> M rows 100..199
  float* XT = U;                 // alias: XT (1024x256) dead before k6 writes U
  float* G = U + NN * HH;        // 100*100
  float* y0v = G + TT * TT;      // 100
  float* errT = y0v + TT;        // 100
  float* e_r = errT + TT;        // 100
  float* wf = e_r + NN;          // 8192

  k0_xpose<<<dim3(32, 8), 256, 0, stream>>>(xt, xr, XT);
  k1_hidden5<<<512, 512, 0, stream>>>(XT, W, bias, Hall);
  k2_gram4<<<88, 256, 0, stream>>>(Ht, w0, G, y0v);
  k3_solve<<<1, 64, 0, stream>>>(G, y0v, yt, errT);
  k4_colscan<<<HH / 64, 64, 0, stream>>>(Ht, errT, w0, Ct, wf);
  k5_pred<<<NN, 256, 0, stream>>>(Hr, wf, yr, e_r);
  k6_mbuild<<<HH / 64, 64, 0, stream>>>(Hr, e_r, wf, Ct, U, out + 1 + DD * HH, out);
  k7_gw4<<<dim3(8, 64), 256, 0, stream>>>(xt, xr, Ct, out + 1);
}